// Round 4
// baseline (6362.930 us; speedup 1.0000x reference)
//
#include <hip/hip_runtime.h>
#include <math.h>

namespace {

constexpr int   STEPS = 100;
constexpr int   BATCH = 2048;
constexpr float DT    = 0.05f;
constexpr float DAMP  = 0.01f;
constexpr float EPSV  = 1e-8f;
constexpr int   NT    = 2;   // trajectories per wave (1 pair)
constexpr int   LDW   = 132; // 16B-aligned rows, odd-mod-32 bank stride

__device__ __forceinline__ float wsum(float v) {
#pragma unroll
  for (int o = 32; o > 0; o >>= 1) v += __shfl_xor(v, o, 64);
  return v;
}

// broadcast lane l's value of v to all lanes via SGPR (no DS pipe)
__device__ __forceinline__ float rl(float v, int l) {
  return __int_as_float(__builtin_amdgcn_readlane(__float_as_int(v), l));
}

__global__ __launch_bounds__(256, 2)
void geo_scramble_kernel(const float* __restrict__ q0g, const float* __restrict__ pdg,
                         const float* __restrict__ W1g, const float* __restrict__ b1g,
                         const float* __restrict__ W2g, const float* __restrict__ b2g,
                         const float* __restrict__ W3g, float* __restrict__ out)
{
  // W1s[i][h] : [64][LDW]   W2Ts[j][k] : [64][LDW]  (W2Ts[j][k] = W2[k][j])
  __shared__ __align__(16) float W1s[64 * LDW];
  __shared__ __align__(16) float W2Ts[64 * LDW];

  const int tid  = threadIdx.x;
  const int lane = tid & 63;
  const int wave = tid >> 6;

  for (int idx = tid; idx < 64 * 128; idx += 256) {
    int r = idx >> 7, c = idx & 127;
    W1s[r * LDW + c] = W1g[idx];
  }
  for (int idx = tid; idx < 64 * 128; idx += 256) {
    int j = idx >> 7, k = idx & 127;
    W2Ts[j * LDW + k] = W2g[k * 64 + j];
  }
  __syncthreads();

  // L2-forward weights resident in VGPRs: lane j holds W2T row j (128 floats)
  float4 w2t[32];
#pragma unroll
  for (int kk = 0; kk < 32; ++kk) w2t[kk] = *(const float4*)&W2Ts[lane * LDW + 4 * kk];

  const float rb10 = b1g[2 * lane];
  const float rb11 = b1g[2 * lane + 1];
  const float rb2  = b2g[lane];
  const float rw3  = W3g[lane];

  const int pair = blockIdx.x * 4 + wave;  // one (base, perturbed) pair per wave
  const int l2 = lane << 1;

  float q[NT], p[NT], g[NT];
#pragma unroll
  for (int t = 0; t < NT; ++t) {
    float base = q0g[pair * 64 + lane];
    if (t & 1) {
      float qp = base + 1e-4f * pdg[pair * 64 + lane];
      float n  = sqrtf(wsum(qp * qp));
      float sc = (n > 0.99f) ? (0.99f / (n + EPSV)) : 1.0f;
      q[t] = qp * sc;
    } else {
      q[t] = base;
    }
    p[t] = 0.0f;
  }

  // Batched gradient of V(q) = W3 . silu(W2 . silu(W1 q + b1) + b2).
  // Lane j owns latent dim j and hidden dims {2j, 2j+1}. Activation
  // broadcasts use v_readlane (SGPR), not LDS.
  auto evalgrad = [&](const float* x, float* gr) {
    // ---- layer1 forward: z1 = W1^T q + b1 ----
    float a0[NT], a1[NT];
#pragma unroll
    for (int t = 0; t < NT; ++t) { a0[t] = rb10; a1[t] = rb11; }
#pragma unroll
    for (int i = 0; i < 64; i += 4) {
#pragma unroll
      for (int u = 0; u < 4; ++u) {
        float2 w = *(const float2*)&W1s[(i + u) * LDW + l2];
#pragma unroll
        for (int t = 0; t < NT; ++t) {
          float s = rl(x[t], i + u);
          a0[t] = fmaf(s, w.x, a0[t]);
          a1[t] = fmaf(s, w.y, a1[t]);
        }
      }
    }

    // silu + derivative (registers only)
    float d10[NT], d11[NT], h0[NT], h1[NT];
#pragma unroll
    for (int t = 0; t < NT; ++t) {
      float z  = a0[t];
      float s  = 1.0f / (1.0f + expf(-z));
      h0[t]    = z * s;
      d10[t]   = s * (1.0f + z * (1.0f - s));
      float zb = a1[t];
      float sb = 1.0f / (1.0f + expf(-zb));
      h1[t]    = zb * sb;
      d11[t]   = sb * (1.0f + zb * (1.0f - sb));
    }

    // ---- layer2 forward: z2 = W2^T h1 + b2 (weights in VGPR, h via readlane) ----
    float a2[NT];
#pragma unroll
    for (int t = 0; t < NT; ++t) a2[t] = rb2;
#pragma unroll
    for (int k = 0; k < 128; k += 4) {
      float4 w = w2t[k >> 2];
#pragma unroll
      for (int t = 0; t < NT; ++t) {
        a2[t] = fmaf(rl(h0[t], k >> 1), w.x, a2[t]);
        a2[t] = fmaf(rl(h1[t], k >> 1), w.y, a2[t]);
        a2[t] = fmaf(rl(h0[t], (k >> 1) + 1), w.z, a2[t]);
        a2[t] = fmaf(rl(h1[t], (k >> 1) + 1), w.w, a2[t]);
      }
    }

    // g2 = W3 * silu'(z2) (registers only)
    float g2r[NT];
#pragma unroll
    for (int t = 0; t < NT; ++t) {
      float z = a2[t];
      float s = 1.0f / (1.0f + expf(-z));
      g2r[t]  = rw3 * (s * (1.0f + z * (1.0f - s)));
    }

    // ---- backward through W2: gh1[k] = sum_j g2[j] * W2[k][j] ----
    float c0[NT], c1[NT];
#pragma unroll
    for (int t = 0; t < NT; ++t) { c0[t] = 0.0f; c1[t] = 0.0f; }
#pragma unroll
    for (int j = 0; j < 64; j += 4) {
#pragma unroll
      for (int u = 0; u < 4; ++u) {
        float2 w = *(const float2*)&W2Ts[(j + u) * LDW + l2];
#pragma unroll
        for (int t = 0; t < NT; ++t) {
          float s = rl(g2r[t], j + u);
          c0[t] = fmaf(s, w.x, c0[t]);
          c1[t] = fmaf(s, w.y, c1[t]);
        }
      }
    }

    // g1 = gh1 * silu'(z1) (registers only)
    float gg0[NT], gg1[NT];
#pragma unroll
    for (int t = 0; t < NT; ++t) {
      gg0[t] = c0[t] * d10[t];
      gg1[t] = c1[t] * d11[t];
    }

    // ---- backward through W1: grad[i] = sum_k g1[k] * W1[i][k] ----
#pragma unroll
    for (int t = 0; t < NT; ++t) gr[t] = 0.0f;
#pragma unroll
    for (int k = 0; k < 128; k += 4) {
      float4 w = *(const float4*)&W1s[lane * LDW + k];
#pragma unroll
      for (int t = 0; t < NT; ++t) {
        gr[t] = fmaf(rl(gg0[t], k >> 1), w.x, gr[t]);
        gr[t] = fmaf(rl(gg1[t], k >> 1), w.y, gr[t]);
        gr[t] = fmaf(rl(gg0[t], (k >> 1) + 1), w.z, gr[t]);
        gr[t] = fmaf(rl(gg1[t], (k >> 1) + 1), w.w, gr[t]);
      }
    }
  };

  evalgrad(q, g);  // gradV at initial positions

  for (int s = 0; s < STEPS; ++s) {
    // distance BEFORE leapfrog (matches scan order)
    {
      float xq = q[0], yq = q[1];
      float df = xq - yq;
      float d2 = wsum(df * df);
      float x2 = fminf(wsum(xq * xq), 0.999f);
      float y2 = fminf(wsum(yq * yq), 0.999f);
      float arg = 1.0f + 2.0f * d2 / ((1.0f - x2) * (1.0f - y2) + EPSV);
      float d = acoshf(fmaxf(arg, 1.0f + EPSV));
      if (lane == 0) out[s * BATCH + pair] = d;
    }

    float qn[NT], ph[NT];
#pragma unroll
    for (int t = 0; t < NT; ++t) {
      ph[t] = (p[t] - 0.5f * DT * g[t]) * (1.0f - DAMP);
      float q2r = wsum(q[t] * q[t]);
      float q2c = fminf(q2r, 0.999f);
      float lam = 2.0f / (1.0f - q2c);
      float v   = DT * ph[t] / (lam * lam);
      // exp_map(q, v)
      float vn  = sqrtf(wsum(v * v)) + EPSV;
      float mag = tanhf(fminf(lam * vn * 0.5f, 15.0f));
      float y   = mag * (v / vn);
      // mobius_add(q, y)  (x2 UNclamped here, per reference)
      float y2  = wsum(y * y);
      float xy  = wsum(q[t] * y);
      float num = (1.0f + 2.0f * xy + y2) * q[t] + (1.0f - q2r) * y;
      float den = 1.0f + 2.0f * xy + q2r * y2;
      float r   = num / (den + EPSV);
      float rn  = sqrtf(wsum(r * r));
      float sc  = (rn > 0.99f) ? (0.99f / (rn + EPSV)) : 1.0f;
      qn[t] = r * sc;
    }

    evalgrad(qn, g);  // gradV(q_new); also next step's gradV(q)
#pragma unroll
    for (int t = 0; t < NT; ++t) {
      p[t] = ph[t] - 0.5f * DT * g[t];
      q[t] = qn[t];
    }
  }
}

}  // namespace

extern "C" void kernel_launch(void* const* d_in, const int* in_sizes, int n_in,
                              void* d_out, int out_size, void* d_ws, size_t ws_size,
                              hipStream_t stream) {
  (void)in_sizes; (void)n_in; (void)out_size; (void)d_ws; (void)ws_size;
  const float* q0 = (const float*)d_in[0];
  const float* pd = (const float*)d_in[1];
  const float* W1 = (const float*)d_in[2];
  const float* b1 = (const float*)d_in[3];
  const float* W2 = (const float*)d_in[4];
  const float* b2 = (const float*)d_in[5];
  const float* W3 = (const float*)d_in[6];
  // d_in[7] = b3: constant offset, does not affect gradV or distances.
  float* out = (float*)d_out;

  geo_scramble_kernel<<<dim3(512), dim3(256), 0, stream>>>(q0, pd, W1, b1, W2, b2, W3, out);
}

// Round 5
// 5938.289 us; speedup vs baseline: 1.0715x; 1.0715x over previous
//
#include <hip/hip_runtime.h>
#include <math.h>

namespace {

constexpr int   STEPS = 100;
constexpr int   BATCH = 2048;
constexpr float DT    = 0.05f;
constexpr float DAMP  = 0.01f;
constexpr float EPSV  = 1e-8f;
constexpr int   NT    = 2;   // trajectories per wave (1 pair)
constexpr int   LDW   = 132; // 16B-aligned rows, odd-mod-32 bank stride (0 conflicts measured)

__device__ __forceinline__ float wsum(float v) {
#pragma unroll
  for (int o = 32; o > 0; o >>= 1) v += __shfl_xor(v, o, 64);
  return v;
}

// broadcast lane l's value of v to all lanes via SGPR (no DS-pipe data path)
__device__ __forceinline__ float rl(float v, int l) {
  return __int_as_float(__builtin_amdgcn_readlane(__float_as_int(v), l));
}

__global__ __launch_bounds__(256, 2)
void geo_scramble_kernel(const float* __restrict__ q0g, const float* __restrict__ pdg,
                         const float* __restrict__ W1g, const float* __restrict__ b1g,
                         const float* __restrict__ W2g, const float* __restrict__ b2g,
                         const float* __restrict__ W3g, float* __restrict__ out)
{
  // W1s[i][h] : [64][LDW]   W2Ts[j][k] : [64][LDW]  (W2Ts[j][k] = W2[k][j])
  __shared__ __align__(16) float W1s[64 * LDW];
  __shared__ __align__(16) float W2Ts[64 * LDW];

  const int tid  = threadIdx.x;
  const int lane = tid & 63;
  const int wave = tid >> 6;

  for (int idx = tid; idx < 64 * 128; idx += 256) {
    int r = idx >> 7, c = idx & 127;
    W1s[r * LDW + c] = W1g[idx];
  }
  for (int idx = tid; idx < 64 * 128; idx += 256) {
    int j = idx >> 7, k = idx & 127;
    W2Ts[j * LDW + k] = W2g[k * 64 + j];
  }
  __syncthreads();

  const float rb10 = b1g[2 * lane];
  const float rb11 = b1g[2 * lane + 1];
  const float rb2  = b2g[lane];
  const float rw3  = W3g[lane];

  const int pair = blockIdx.x * 4 + wave;  // one (base, perturbed) pair per wave
  const int l2 = lane << 1;

  float q[NT], p[NT], g[NT];
#pragma unroll
  for (int t = 0; t < NT; ++t) {
    float base = q0g[pair * 64 + lane];
    if (t & 1) {
      float qp = base + 1e-4f * pdg[pair * 64 + lane];
      float n  = sqrtf(wsum(qp * qp));
      float sc = (n > 0.99f) ? (0.99f / (n + EPSV)) : 1.0f;
      q[t] = qp * sc;
    } else {
      q[t] = base;
    }
    p[t] = 0.0f;
  }

  // Batched gradient of V(q) = W3 . silu(W2 . silu(W1 q + b1) + b2).
  // Lane j owns latent dim j and hidden dims {2j, 2j+1}. Activation
  // broadcasts via v_readlane (SGPR); weights stream from LDS only.
  auto evalgrad = [&](const float* x, float* gr) {
    // ---- layer1 forward: z1 = W1^T q + b1 ----
    float a0[NT], a1[NT];
#pragma unroll
    for (int t = 0; t < NT; ++t) { a0[t] = rb10; a1[t] = rb11; }
#pragma unroll
    for (int i = 0; i < 64; i += 4) {
      float2 w0 = *(const float2*)&W1s[(i + 0) * LDW + l2];
      float2 w1 = *(const float2*)&W1s[(i + 1) * LDW + l2];
      float2 w2 = *(const float2*)&W1s[(i + 2) * LDW + l2];
      float2 w3 = *(const float2*)&W1s[(i + 3) * LDW + l2];
#pragma unroll
      for (int t = 0; t < NT; ++t) {
        float s0 = rl(x[t], i + 0), s1 = rl(x[t], i + 1);
        float s2 = rl(x[t], i + 2), s3 = rl(x[t], i + 3);
        a0[t] = fmaf(s0, w0.x, a0[t]); a1[t] = fmaf(s0, w0.y, a1[t]);
        a0[t] = fmaf(s1, w1.x, a0[t]); a1[t] = fmaf(s1, w1.y, a1[t]);
        a0[t] = fmaf(s2, w2.x, a0[t]); a1[t] = fmaf(s2, w2.y, a1[t]);
        a0[t] = fmaf(s3, w3.x, a0[t]); a1[t] = fmaf(s3, w3.y, a1[t]);
      }
    }

    // silu + derivative (registers only)
    float d10[NT], d11[NT], h0[NT], h1[NT];
#pragma unroll
    for (int t = 0; t < NT; ++t) {
      float z  = a0[t];
      float s  = 1.0f / (1.0f + expf(-z));
      h0[t]    = z * s;
      d10[t]   = s * (1.0f + z * (1.0f - s));
      float zb = a1[t];
      float sb = 1.0f / (1.0f + expf(-zb));
      h1[t]    = zb * sb;
      d11[t]   = sb * (1.0f + zb * (1.0f - sb));
    }

    // ---- layer2 forward: z2 = W2^T h1 + b2 ----
    float a2[NT];
#pragma unroll
    for (int t = 0; t < NT; ++t) a2[t] = rb2;
#pragma unroll
    for (int k = 0; k < 128; k += 4) {
      float4 w = *(const float4*)&W2Ts[lane * LDW + k];
#pragma unroll
      for (int t = 0; t < NT; ++t) {
        a2[t] = fmaf(rl(h0[t], k >> 1), w.x, a2[t]);
        a2[t] = fmaf(rl(h1[t], k >> 1), w.y, a2[t]);
        a2[t] = fmaf(rl(h0[t], (k >> 1) + 1), w.z, a2[t]);
        a2[t] = fmaf(rl(h1[t], (k >> 1) + 1), w.w, a2[t]);
      }
    }

    // g2 = W3 * silu'(z2) (registers only)
    float g2r[NT];
#pragma unroll
    for (int t = 0; t < NT; ++t) {
      float z = a2[t];
      float s = 1.0f / (1.0f + expf(-z));
      g2r[t]  = rw3 * (s * (1.0f + z * (1.0f - s)));
    }

    // ---- backward through W2: gh1[k] = sum_j g2[j] * W2[k][j] ----
    float c0[NT], c1[NT];
#pragma unroll
    for (int t = 0; t < NT; ++t) { c0[t] = 0.0f; c1[t] = 0.0f; }
#pragma unroll
    for (int j = 0; j < 64; j += 4) {
      float2 w0 = *(const float2*)&W2Ts[(j + 0) * LDW + l2];
      float2 w1 = *(const float2*)&W2Ts[(j + 1) * LDW + l2];
      float2 w2 = *(const float2*)&W2Ts[(j + 2) * LDW + l2];
      float2 w3 = *(const float2*)&W2Ts[(j + 3) * LDW + l2];
#pragma unroll
      for (int t = 0; t < NT; ++t) {
        float s0 = rl(g2r[t], j + 0), s1 = rl(g2r[t], j + 1);
        float s2 = rl(g2r[t], j + 2), s3 = rl(g2r[t], j + 3);
        c0[t] = fmaf(s0, w0.x, c0[t]); c1[t] = fmaf(s0, w0.y, c1[t]);
        c0[t] = fmaf(s1, w1.x, c0[t]); c1[t] = fmaf(s1, w1.y, c1[t]);
        c0[t] = fmaf(s2, w2.x, c0[t]); c1[t] = fmaf(s2, w2.y, c1[t]);
        c0[t] = fmaf(s3, w3.x, c0[t]); c1[t] = fmaf(s3, w3.y, c1[t]);
      }
    }

    // g1 = gh1 * silu'(z1) (registers only)
    float gg0[NT], gg1[NT];
#pragma unroll
    for (int t = 0; t < NT; ++t) {
      gg0[t] = c0[t] * d10[t];
      gg1[t] = c1[t] * d11[t];
    }

    // ---- backward through W1: grad[i] = sum_k g1[k] * W1[i][k] ----
#pragma unroll
    for (int t = 0; t < NT; ++t) gr[t] = 0.0f;
#pragma unroll
    for (int k = 0; k < 128; k += 4) {
      float4 w = *(const float4*)&W1s[lane * LDW + k];
#pragma unroll
      for (int t = 0; t < NT; ++t) {
        gr[t] = fmaf(rl(gg0[t], k >> 1), w.x, gr[t]);
        gr[t] = fmaf(rl(gg1[t], k >> 1), w.y, gr[t]);
        gr[t] = fmaf(rl(gg0[t], (k >> 1) + 1), w.z, gr[t]);
        gr[t] = fmaf(rl(gg1[t], (k >> 1) + 1), w.w, gr[t]);
      }
    }
  };

  evalgrad(q, g);  // gradV at initial positions

  for (int s = 0; s < STEPS; ++s) {
    // distance BEFORE leapfrog (matches scan order)
    {
      float xq = q[0], yq = q[1];
      float df = xq - yq;
      float d2 = wsum(df * df);
      float x2 = fminf(wsum(xq * xq), 0.999f);
      float y2 = fminf(wsum(yq * yq), 0.999f);
      float arg = 1.0f + 2.0f * d2 / ((1.0f - x2) * (1.0f - y2) + EPSV);
      float d = acoshf(fmaxf(arg, 1.0f + EPSV));
      if (lane == 0) out[s * BATCH + pair] = d;
    }

    float qn[NT], ph[NT];
#pragma unroll
    for (int t = 0; t < NT; ++t) {
      ph[t] = (p[t] - 0.5f * DT * g[t]) * (1.0f - DAMP);
      float q2r = wsum(q[t] * q[t]);
      float q2c = fminf(q2r, 0.999f);
      float lam = 2.0f / (1.0f - q2c);
      float v   = DT * ph[t] / (lam * lam);
      // exp_map(q, v)
      float vn  = sqrtf(wsum(v * v)) + EPSV;
      float mag = tanhf(fminf(lam * vn * 0.5f, 15.0f));
      float y   = mag * (v / vn);
      // mobius_add(q, y)  (x2 UNclamped here, per reference)
      float y2  = wsum(y * y);
      float xy  = wsum(q[t] * y);
      float num = (1.0f + 2.0f * xy + y2) * q[t] + (1.0f - q2r) * y;
      float den = 1.0f + 2.0f * xy + q2r * y2;
      float r   = num / (den + EPSV);
      float rn  = sqrtf(wsum(r * r));
      float sc  = (rn > 0.99f) ? (0.99f / (rn + EPSV)) : 1.0f;
      qn[t] = r * sc;
    }

    evalgrad(qn, g);  // gradV(q_new); also next step's gradV(q)
#pragma unroll
    for (int t = 0; t < NT; ++t) {
      p[t] = ph[t] - 0.5f * DT * g[t];
      q[t] = qn[t];
    }
  }
}

}  // namespace

extern "C" void kernel_launch(void* const* d_in, const int* in_sizes, int n_in,
                              void* d_out, int out_size, void* d_ws, size_t ws_size,
                              hipStream_t stream) {
  (void)in_sizes; (void)n_in; (void)out_size; (void)d_ws; (void)ws_size;
  const float* q0 = (const float*)d_in[0];
  const float* pd = (const float*)d_in[1];
  const float* W1 = (const float*)d_in[2];
  const float* b1 = (const float*)d_in[3];
  const float* W2 = (const float*)d_in[4];
  const float* b2 = (const float*)d_in[5];
  const float* W3 = (const float*)d_in[6];
  // d_in[7] = b3: constant offset, does not affect gradV or distances.
  float* out = (float*)d_out;

  geo_scramble_kernel<<<dim3(512), dim3(256), 0, stream>>>(q0, pd, W1, b1, W2, b2, W3, out);
}

// Round 6
// 4899.639 us; speedup vs baseline: 1.2987x; 1.2120x over previous
//
#include <hip/hip_runtime.h>
#include <math.h>

namespace {

constexpr int   STEPS = 100;
constexpr int   BATCH = 2048;
constexpr float DT    = 0.05f;
constexpr float DAMP  = 0.01f;
constexpr float EPSV  = 1e-8f;
constexpr int   LDW   = 132; // 16B-aligned rows, odd-mod-32 bank stride (0 conflicts measured)

__device__ __forceinline__ float wsum(float v) {
#pragma unroll
  for (int o = 32; o > 0; o >>= 1) v += __shfl_xor(v, o, 64);
  return v;
}

// broadcast lane l's value of v to all lanes via SGPR (VALU op, no DS traffic)
__device__ __forceinline__ float rl(float v, int l) {
  return __int_as_float(__builtin_amdgcn_readlane(__float_as_int(v), l));
}

__global__ __launch_bounds__(256, 2)
void geo_scramble_kernel(const float* __restrict__ q0g, const float* __restrict__ pdg,
                         const float* __restrict__ W1g, const float* __restrict__ b1g,
                         const float* __restrict__ W2g, const float* __restrict__ b2g,
                         const float* __restrict__ W3g, float* __restrict__ out)
{
  // W1s[i][h] : [64][LDW]   W2Ts[j][k] : [64][LDW]  (W2Ts[j][k] = W2[k][j])
  __shared__ __align__(16) float W1s[64 * LDW];
  __shared__ __align__(16) float W2Ts[64 * LDW];
  __shared__ __align__(16) float stg_all[4][2][128];  // BW1 g1 broadcast staging

  const int tid  = threadIdx.x;
  const int lane = tid & 63;
  const int wave = tid >> 6;

  for (int idx = tid; idx < 64 * 128; idx += 256) {
    int r = idx >> 7, c = idx & 127;
    W1s[r * LDW + c] = W1g[idx];
  }
  for (int idx = tid; idx < 64 * 128; idx += 256) {
    int j = idx >> 7, k = idx & 127;
    W2Ts[j * LDW + k] = W2g[k * 64 + j];
  }
  __syncthreads();

  const float rb10 = b1g[2 * lane];
  const float rb11 = b1g[2 * lane + 1];
  const float rb2  = b2g[lane];
  const float rw3  = W3g[lane];

  float* stgA = &stg_all[wave][0][0];
  float* stgB = &stg_all[wave][1][0];
  const int pair = blockIdx.x * 4 + wave;  // one (base, perturbed) pair per wave
  const int l2 = lane << 1;

  // ---- init (named scalars only; no local arrays anywhere in the hot path) ----
  float qA = q0g[pair * 64 + lane];
  float qB;
  {
    float qp = qA + 1e-4f * pdg[pair * 64 + lane];
    float n  = sqrtf(wsum(qp * qp));
    float sc = (n > 0.99f) ? (0.99f / (n + EPSV)) : 1.0f;
    qB = qp * sc;
  }
  float pA = 0.0f, pB = 0.0f, gA, gB;

  // Batched gradient of V(q) = W3 . silu(W2 . silu(W1 q + b1) + b2) for the
  // two trajectories. Lane j owns latent dim j and hidden dims {2j, 2j+1}.
  // Broadcasts: readlane (L1 fwd, L2 fwd, BW2); LDS-staged (BW1) to balance
  // the VALU and DS pipes.
  auto evalgrad = [&](float xA, float xB, float& grA, float& grB) {
    // ---- layer1 forward: z1 = W1^T q + b1 ----
    float a0A = rb10, a1A = rb11, a0B = rb10, a1B = rb11;
#pragma unroll
    for (int i = 0; i < 64; i += 4) {
      float2 w0 = *(const float2*)&W1s[(i + 0) * LDW + l2];
      float2 w1 = *(const float2*)&W1s[(i + 1) * LDW + l2];
      float2 w2 = *(const float2*)&W1s[(i + 2) * LDW + l2];
      float2 w3 = *(const float2*)&W1s[(i + 3) * LDW + l2];
      float sA, sB;
      sA = rl(xA, i + 0); sB = rl(xB, i + 0);
      a0A = fmaf(sA, w0.x, a0A); a1A = fmaf(sA, w0.y, a1A);
      a0B = fmaf(sB, w0.x, a0B); a1B = fmaf(sB, w0.y, a1B);
      sA = rl(xA, i + 1); sB = rl(xB, i + 1);
      a0A = fmaf(sA, w1.x, a0A); a1A = fmaf(sA, w1.y, a1A);
      a0B = fmaf(sB, w1.x, a0B); a1B = fmaf(sB, w1.y, a1B);
      sA = rl(xA, i + 2); sB = rl(xB, i + 2);
      a0A = fmaf(sA, w2.x, a0A); a1A = fmaf(sA, w2.y, a1A);
      a0B = fmaf(sB, w2.x, a0B); a1B = fmaf(sB, w2.y, a1B);
      sA = rl(xA, i + 3); sB = rl(xB, i + 3);
      a0A = fmaf(sA, w3.x, a0A); a1A = fmaf(sA, w3.y, a1A);
      a0B = fmaf(sB, w3.x, a0B); a1B = fmaf(sB, w3.y, a1B);
    }

    // silu + derivative (registers only)
    float sA0 = 1.0f / (1.0f + expf(-a0A));
    float h0A = a0A * sA0;
    float d10A = sA0 * (1.0f + a0A * (1.0f - sA0));
    float sA1 = 1.0f / (1.0f + expf(-a1A));
    float h1A = a1A * sA1;
    float d11A = sA1 * (1.0f + a1A * (1.0f - sA1));
    float sB0 = 1.0f / (1.0f + expf(-a0B));
    float h0B = a0B * sB0;
    float d10B = sB0 * (1.0f + a0B * (1.0f - sB0));
    float sB1 = 1.0f / (1.0f + expf(-a1B));
    float h1B = a1B * sB1;
    float d11B = sB1 * (1.0f + a1B * (1.0f - sB1));

    // ---- layer2 forward: z2 = W2^T h1 + b2 ----
    float a2A = rb2, a2B = rb2;
#pragma unroll
    for (int k = 0; k < 128; k += 4) {
      float4 w = *(const float4*)&W2Ts[lane * LDW + k];
      int m = k >> 1;
      float s0A = rl(h0A, m),     s0B = rl(h0B, m);
      float s1A = rl(h1A, m),     s1B = rl(h1B, m);
      float s2A = rl(h0A, m + 1), s2B = rl(h0B, m + 1);
      float s3A = rl(h1A, m + 1), s3B = rl(h1B, m + 1);
      a2A = fmaf(s0A, w.x, a2A); a2B = fmaf(s0B, w.x, a2B);
      a2A = fmaf(s1A, w.y, a2A); a2B = fmaf(s1B, w.y, a2B);
      a2A = fmaf(s2A, w.z, a2A); a2B = fmaf(s2B, w.z, a2B);
      a2A = fmaf(s3A, w.w, a2A); a2B = fmaf(s3B, w.w, a2B);
    }

    // g2 = W3 * silu'(z2) (registers only)
    float t2A = 1.0f / (1.0f + expf(-a2A));
    float g2A = rw3 * (t2A * (1.0f + a2A * (1.0f - t2A)));
    float t2B = 1.0f / (1.0f + expf(-a2B));
    float g2B = rw3 * (t2B * (1.0f + a2B * (1.0f - t2B)));

    // ---- backward through W2: gh1[k] = sum_j g2[j] * W2[k][j] ----
    float c0A = 0.0f, c1A = 0.0f, c0B = 0.0f, c1B = 0.0f;
#pragma unroll
    for (int j = 0; j < 64; j += 4) {
      float2 w0 = *(const float2*)&W2Ts[(j + 0) * LDW + l2];
      float2 w1 = *(const float2*)&W2Ts[(j + 1) * LDW + l2];
      float2 w2 = *(const float2*)&W2Ts[(j + 2) * LDW + l2];
      float2 w3 = *(const float2*)&W2Ts[(j + 3) * LDW + l2];
      float sA, sB;
      sA = rl(g2A, j + 0); sB = rl(g2B, j + 0);
      c0A = fmaf(sA, w0.x, c0A); c1A = fmaf(sA, w0.y, c1A);
      c0B = fmaf(sB, w0.x, c0B); c1B = fmaf(sB, w0.y, c1B);
      sA = rl(g2A, j + 1); sB = rl(g2B, j + 1);
      c0A = fmaf(sA, w1.x, c0A); c1A = fmaf(sA, w1.y, c1A);
      c0B = fmaf(sB, w1.x, c0B); c1B = fmaf(sB, w1.y, c1B);
      sA = rl(g2A, j + 2); sB = rl(g2B, j + 2);
      c0A = fmaf(sA, w2.x, c0A); c1A = fmaf(sA, w2.y, c1A);
      c0B = fmaf(sB, w2.x, c0B); c1B = fmaf(sB, w2.y, c1B);
      sA = rl(g2A, j + 3); sB = rl(g2B, j + 3);
      c0A = fmaf(sA, w3.x, c0A); c1A = fmaf(sA, w3.y, c1A);
      c0B = fmaf(sB, w3.x, c0B); c1B = fmaf(sB, w3.y, c1B);
    }

    // g1 = gh1 * silu'(z1) — stage to LDS for the BW1 broadcast
    {
      float2 ggA; ggA.x = c0A * d10A; ggA.y = c1A * d11A;
      float2 ggB; ggB.x = c0B * d10B; ggB.y = c1B * d11B;
      *(float2*)&stgA[l2] = ggA;
      *(float2*)&stgB[l2] = ggB;
    }

    // ---- backward through W1: grad[i] = sum_k g1[k] * W1[i][k] ----
    float grAl = 0.0f, grBl = 0.0f;
#pragma unroll
    for (int k = 0; k < 128; k += 4) {
      float4 w  = *(const float4*)&W1s[lane * LDW + k];
      float4 bA = *(const float4*)&stgA[k];
      float4 bB = *(const float4*)&stgB[k];
      grAl = fmaf(bA.x, w.x, grAl); grBl = fmaf(bB.x, w.x, grBl);
      grAl = fmaf(bA.y, w.y, grAl); grBl = fmaf(bB.y, w.y, grBl);
      grAl = fmaf(bA.z, w.z, grAl); grBl = fmaf(bB.z, w.z, grBl);
      grAl = fmaf(bA.w, w.w, grAl); grBl = fmaf(bB.w, w.w, grBl);
    }
    grA = grAl; grB = grBl;
  };

  // one leapfrog half: returns q_new and p_half (named-scalar in/out)
  auto leapq = [&](float qv, float pv, float gv, float& qn_out, float& ph_out) {
    float ph  = (pv - 0.5f * DT * gv) * (1.0f - DAMP);
    float q2r = wsum(qv * qv);
    float q2c = fminf(q2r, 0.999f);
    float lam = 2.0f / (1.0f - q2c);
    float v   = DT * ph / (lam * lam);
    float vn  = sqrtf(wsum(v * v)) + EPSV;
    float mag = tanhf(fminf(lam * vn * 0.5f, 15.0f));
    float y   = mag * (v / vn);
    float y2  = wsum(y * y);
    float xy  = wsum(qv * y);
    float num = (1.0f + 2.0f * xy + y2) * qv + (1.0f - q2r) * y;
    float den = 1.0f + 2.0f * xy + q2r * y2;
    float r   = num / (den + EPSV);
    float rn  = sqrtf(wsum(r * r));
    float sc  = (rn > 0.99f) ? (0.99f / (rn + EPSV)) : 1.0f;
    qn_out = r * sc;
    ph_out = ph;
  };

  evalgrad(qA, qB, gA, gB);  // gradV at initial positions

  for (int s = 0; s < STEPS; ++s) {
    // distance BEFORE leapfrog (matches scan order)
    {
      float df = qA - qB;
      float d2 = wsum(df * df);
      float x2 = fminf(wsum(qA * qA), 0.999f);
      float y2 = fminf(wsum(qB * qB), 0.999f);
      float arg = 1.0f + 2.0f * d2 / ((1.0f - x2) * (1.0f - y2) + EPSV);
      float d = acoshf(fmaxf(arg, 1.0f + EPSV));
      if (lane == 0) out[s * BATCH + pair] = d;
    }

    float qnA, phA, qnB, phB;
    leapq(qA, pA, gA, qnA, phA);
    leapq(qB, pB, gB, qnB, phB);

    evalgrad(qnA, qnB, gA, gB);  // gradV(q_new); reused as next step's gradV(q)

    pA = phA - 0.5f * DT * gA; qA = qnA;
    pB = phB - 0.5f * DT * gB; qB = qnB;
  }
}

}  // namespace

extern "C" void kernel_launch(void* const* d_in, const int* in_sizes, int n_in,
                              void* d_out, int out_size, void* d_ws, size_t ws_size,
                              hipStream_t stream) {
  (void)in_sizes; (void)n_in; (void)out_size; (void)d_ws; (void)ws_size;
  const float* q0 = (const float*)d_in[0];
  const float* pd = (const float*)d_in[1];
  const float* W1 = (const float*)d_in[2];
  const float* b1 = (const float*)d_in[3];
  const float* W2 = (const float*)d_in[4];
  const float* b2 = (const float*)d_in[5];
  const float* W3 = (const float*)d_in[6];
  // d_in[7] = b3: constant offset, does not affect gradV or distances.
  float* out = (float*)d_out;

  geo_scramble_kernel<<<dim3(512), dim3(256), 0, stream>>>(q0, pd, W1, b1, W2, b2, W3, out);
}

// Round 7
// 4079.770 us; speedup vs baseline: 1.5596x; 1.2010x over previous
//
#include <hip/hip_runtime.h>
#include <math.h>

namespace {

constexpr int   STEPS = 100;
constexpr int   BATCH = 2048;
constexpr float DT    = 0.05f;
constexpr float DAMP  = 0.01f;
constexpr float EPSV  = 1e-8f;
constexpr int   LDW   = 132; // 16B-aligned rows, odd-mod-32 bank stride (0 conflicts measured)

__device__ __forceinline__ float wsum(float v) {
#pragma unroll
  for (int o = 32; o > 0; o >>= 1) v += __shfl_xor(v, o, 64);
  return v;
}

__global__ __launch_bounds__(256, 2)
void geo_scramble_kernel(const float* __restrict__ q0g, const float* __restrict__ pdg,
                         const float* __restrict__ W1g, const float* __restrict__ b1g,
                         const float* __restrict__ W2g, const float* __restrict__ b2g,
                         const float* __restrict__ W3g, float* __restrict__ out)
{
  // W1s[i][h] : [64][LDW]   W2Ts[j][k] : [64][LDW]  (W2Ts[j][k] = W2[k][j])
  __shared__ __align__(16) float W1s[64 * LDW];
  __shared__ __align__(16) float W2Ts[64 * LDW];
  __shared__ __align__(16) float stg_all[4][2][128];  // per-wave broadcast staging

  const int tid  = threadIdx.x;
  const int lane = tid & 63;
  const int wave = tid >> 6;

  for (int idx = tid; idx < 64 * 128; idx += 256) {
    int r = idx >> 7, c = idx & 127;
    W1s[r * LDW + c] = W1g[idx];
  }
  for (int idx = tid; idx < 64 * 128; idx += 256) {
    int j = idx >> 7, k = idx & 127;
    W2Ts[j * LDW + k] = W2g[k * 64 + j];
  }
  __syncthreads();

  const float rb10 = b1g[2 * lane];
  const float rb11 = b1g[2 * lane + 1];
  const float rb2  = b2g[lane];
  const float rw3  = W3g[lane];

  float* stgA = &stg_all[wave][0][0];
  float* stgB = &stg_all[wave][1][0];
  const int pair = blockIdx.x * 4 + wave;  // one (base, perturbed) pair per wave
  const int l2 = lane << 1;

  float qA = q0g[pair * 64 + lane];
  float qB;
  {
    float qp = qA + 1e-4f * pdg[pair * 64 + lane];
    float n  = sqrtf(wsum(qp * qp));
    float sc = (n > 0.99f) ? (0.99f / (n + EPSV)) : 1.0f;
    qB = qp * sc;
  }
  float pA = 0.0f, pB = 0.0f, gA, gB;

  // Batched gradient of V(q) = W3 . silu(W2 . silu(W1 q + b1) + b2).
  // Lane j owns latent dim j and hidden dims {2j, 2j+1}. All broadcasts via
  // LDS staging (R2-proven). Every phase: full unroll + depth-2 software
  // pipeline (block n+1 loads issue before block n FMAs), named regs only.
  // Per-accumulator FMA order identical to the R2 kernel (bitwise-stable).
  auto evalgrad = [&](float xA, float xB, float& grA, float& grB) {
    stgA[lane] = xA;
    stgB[lane] = xB;

    // ---- layer1 forward: z1 = W1^T q + b1 ----
    float a0A = rb10, a1A = rb11, a0B = rb10, a1B = rb11;
    {
      auto ld = [&](int i, float2& u0, float2& u1, float2& u2, float2& u3,
                    float4& vA, float4& vB) {
        u0 = *(const float2*)&W1s[(i + 0) * LDW + l2];
        u1 = *(const float2*)&W1s[(i + 1) * LDW + l2];
        u2 = *(const float2*)&W1s[(i + 2) * LDW + l2];
        u3 = *(const float2*)&W1s[(i + 3) * LDW + l2];
        vA = *(const float4*)&stgA[i];
        vB = *(const float4*)&stgB[i];
      };
      float2 w0, w1, w2, w3; float4 bA, bB;
      ld(0, w0, w1, w2, w3, bA, bB);
#pragma unroll
      for (int i = 0; i < 64; i += 4) {
        float2 n0, n1, n2, n3; float4 nA, nB;
        if (i + 4 < 64) ld(i + 4, n0, n1, n2, n3, nA, nB);
        a0A = fmaf(bA.x, w0.x, a0A); a1A = fmaf(bA.x, w0.y, a1A);
        a0B = fmaf(bB.x, w0.x, a0B); a1B = fmaf(bB.x, w0.y, a1B);
        a0A = fmaf(bA.y, w1.x, a0A); a1A = fmaf(bA.y, w1.y, a1A);
        a0B = fmaf(bB.y, w1.x, a0B); a1B = fmaf(bB.y, w1.y, a1B);
        a0A = fmaf(bA.z, w2.x, a0A); a1A = fmaf(bA.z, w2.y, a1A);
        a0B = fmaf(bB.z, w2.x, a0B); a1B = fmaf(bB.z, w2.y, a1B);
        a0A = fmaf(bA.w, w3.x, a0A); a1A = fmaf(bA.w, w3.y, a1A);
        a0B = fmaf(bB.w, w3.x, a0B); a1B = fmaf(bB.w, w3.y, a1B);
        w0 = n0; w1 = n1; w2 = n2; w3 = n3; bA = nA; bB = nB;
      }
    }

    // silu + derivative (registers only); stage h to LDS
    float sA0 = 1.0f / (1.0f + expf(-a0A));
    float h0A = a0A * sA0;
    float d10A = sA0 * (1.0f + a0A * (1.0f - sA0));
    float sA1 = 1.0f / (1.0f + expf(-a1A));
    float h1A = a1A * sA1;
    float d11A = sA1 * (1.0f + a1A * (1.0f - sA1));
    float sB0 = 1.0f / (1.0f + expf(-a0B));
    float h0B = a0B * sB0;
    float d10B = sB0 * (1.0f + a0B * (1.0f - sB0));
    float sB1 = 1.0f / (1.0f + expf(-a1B));
    float h1B = a1B * sB1;
    float d11B = sB1 * (1.0f + a1B * (1.0f - sB1));
    {
      float2 hA; hA.x = h0A; hA.y = h1A;
      float2 hB; hB.x = h0B; hB.y = h1B;
      *(float2*)&stgA[l2] = hA;
      *(float2*)&stgB[l2] = hB;
    }

    // ---- layer2 forward: z2 = W2^T h1 + b2 ----
    float a2A = rb2, a2B = rb2;
    {
      auto ld = [&](int k, float4& w, float4& vA, float4& vB) {
        w  = *(const float4*)&W2Ts[lane * LDW + k];
        vA = *(const float4*)&stgA[k];
        vB = *(const float4*)&stgB[k];
      };
      float4 w, bA, bB;
      ld(0, w, bA, bB);
#pragma unroll
      for (int k = 0; k < 128; k += 4) {
        float4 nw, nA, nB;
        if (k + 4 < 128) ld(k + 4, nw, nA, nB);
        a2A = fmaf(bA.x, w.x, a2A);
        a2A = fmaf(bA.y, w.y, a2A);
        a2A = fmaf(bA.z, w.z, a2A);
        a2A = fmaf(bA.w, w.w, a2A);
        a2B = fmaf(bB.x, w.x, a2B);
        a2B = fmaf(bB.y, w.y, a2B);
        a2B = fmaf(bB.z, w.z, a2B);
        a2B = fmaf(bB.w, w.w, a2B);
        w = nw; bA = nA; bB = nB;
      }
    }

    // g2 = W3 * silu'(z2); stage (overwrites x-staging slots 0..63)
    {
      float t2A = 1.0f / (1.0f + expf(-a2A));
      float g2A = rw3 * (t2A * (1.0f + a2A * (1.0f - t2A)));
      float t2B = 1.0f / (1.0f + expf(-a2B));
      float g2B = rw3 * (t2B * (1.0f + a2B * (1.0f - t2B)));
      stgA[lane] = g2A;
      stgB[lane] = g2B;
    }

    // ---- backward through W2: gh1[k] = sum_j g2[j] * W2[k][j] ----
    float c0A = 0.0f, c1A = 0.0f, c0B = 0.0f, c1B = 0.0f;
    {
      auto ld = [&](int j, float2& u0, float2& u1, float2& u2, float2& u3,
                    float4& vA, float4& vB) {
        u0 = *(const float2*)&W2Ts[(j + 0) * LDW + l2];
        u1 = *(const float2*)&W2Ts[(j + 1) * LDW + l2];
        u2 = *(const float2*)&W2Ts[(j + 2) * LDW + l2];
        u3 = *(const float2*)&W2Ts[(j + 3) * LDW + l2];
        vA = *(const float4*)&stgA[j];
        vB = *(const float4*)&stgB[j];
      };
      float2 w0, w1, w2, w3; float4 bA, bB;
      ld(0, w0, w1, w2, w3, bA, bB);
#pragma unroll
      for (int j = 0; j < 64; j += 4) {
        float2 n0, n1, n2, n3; float4 nA, nB;
        if (j + 4 < 64) ld(j + 4, n0, n1, n2, n3, nA, nB);
        c0A = fmaf(bA.x, w0.x, c0A); c1A = fmaf(bA.x, w0.y, c1A);
        c0B = fmaf(bB.x, w0.x, c0B); c1B = fmaf(bB.x, w0.y, c1B);
        c0A = fmaf(bA.y, w1.x, c0A); c1A = fmaf(bA.y, w1.y, c1A);
        c0B = fmaf(bB.y, w1.x, c0B); c1B = fmaf(bB.y, w1.y, c1B);
        c0A = fmaf(bA.z, w2.x, c0A); c1A = fmaf(bA.z, w2.y, c1A);
        c0B = fmaf(bB.z, w2.x, c0B); c1B = fmaf(bB.z, w2.y, c1B);
        c0A = fmaf(bA.w, w3.x, c0A); c1A = fmaf(bA.w, w3.y, c1A);
        c0B = fmaf(bB.w, w3.x, c0B); c1B = fmaf(bB.w, w3.y, c1B);
        w0 = n0; w1 = n1; w2 = n2; w3 = n3; bA = nA; bB = nB;
      }
    }

    // g1 = gh1 * silu'(z1) — stage for the BW1 broadcast
    {
      float2 ggA; ggA.x = c0A * d10A; ggA.y = c1A * d11A;
      float2 ggB; ggB.x = c0B * d10B; ggB.y = c1B * d11B;
      *(float2*)&stgA[l2] = ggA;
      *(float2*)&stgB[l2] = ggB;
    }

    // ---- backward through W1: grad[i] = sum_k g1[k] * W1[i][k] ----
    float grAl = 0.0f, grBl = 0.0f;
    {
      auto ld = [&](int k, float4& w, float4& vA, float4& vB) {
        w  = *(const float4*)&W1s[lane * LDW + k];
        vA = *(const float4*)&stgA[k];
        vB = *(const float4*)&stgB[k];
      };
      float4 w, bA, bB;
      ld(0, w, bA, bB);
#pragma unroll
      for (int k = 0; k < 128; k += 4) {
        float4 nw, nA, nB;
        if (k + 4 < 128) ld(k + 4, nw, nA, nB);
        grAl = fmaf(bA.x, w.x, grAl);
        grAl = fmaf(bA.y, w.y, grAl);
        grAl = fmaf(bA.z, w.z, grAl);
        grAl = fmaf(bA.w, w.w, grAl);
        grBl = fmaf(bB.x, w.x, grBl);
        grBl = fmaf(bB.y, w.y, grBl);
        grBl = fmaf(bB.z, w.z, grBl);
        grBl = fmaf(bB.w, w.w, grBl);
        w = nw; bA = nA; bB = nB;
      }
    }
    grA = grAl; grB = grBl;
  };

  evalgrad(qA, qB, gA, gB);  // gradV at initial positions (cold path, once)

  for (int s = 0; s < STEPS; ++s) {
    // distance BEFORE leapfrog (matches scan order)
    {
      float df = qA - qB;
      float d2 = wsum(df * df);
      float x2 = fminf(wsum(qA * qA), 0.999f);
      float y2 = fminf(wsum(qB * qB), 0.999f);
      float arg = 1.0f + 2.0f * d2 / ((1.0f - x2) * (1.0f - y2) + EPSV);
      float d = acoshf(fmaxf(arg, 1.0f + EPSV));
      if (lane == 0) out[s * BATCH + pair] = d;
    }

    // leapfrog first half, trajectory A (inline, R2 op sequence)
    float qnA, phA;
    {
      float ph  = (pA - 0.5f * DT * gA) * (1.0f - DAMP);
      float q2r = wsum(qA * qA);
      float q2c = fminf(q2r, 0.999f);
      float lam = 2.0f / (1.0f - q2c);
      float v   = DT * ph / (lam * lam);
      float vn  = sqrtf(wsum(v * v)) + EPSV;
      float mag = tanhf(fminf(lam * vn * 0.5f, 15.0f));
      float y   = mag * (v / vn);
      float y2  = wsum(y * y);
      float xy  = wsum(qA * y);
      float num = (1.0f + 2.0f * xy + y2) * qA + (1.0f - q2r) * y;
      float den = 1.0f + 2.0f * xy + q2r * y2;
      float r   = num / (den + EPSV);
      float rn  = sqrtf(wsum(r * r));
      float sc  = (rn > 0.99f) ? (0.99f / (rn + EPSV)) : 1.0f;
      qnA = r * sc;
      phA = ph;
    }
    // leapfrog first half, trajectory B
    float qnB, phB;
    {
      float ph  = (pB - 0.5f * DT * gB) * (1.0f - DAMP);
      float q2r = wsum(qB * qB);
      float q2c = fminf(q2r, 0.999f);
      float lam = 2.0f / (1.0f - q2c);
      float v   = DT * ph / (lam * lam);
      float vn  = sqrtf(wsum(v * v)) + EPSV;
      float mag = tanhf(fminf(lam * vn * 0.5f, 15.0f));
      float y   = mag * (v / vn);
      float y2  = wsum(y * y);
      float xy  = wsum(qB * y);
      float num = (1.0f + 2.0f * xy + y2) * qB + (1.0f - q2r) * y;
      float den = 1.0f + 2.0f * xy + q2r * y2;
      float r   = num / (den + EPSV);
      float rn  = sqrtf(wsum(r * r));
      float sc  = (rn > 0.99f) ? (0.99f / (rn + EPSV)) : 1.0f;
      qnB = r * sc;
      phB = ph;
    }

    evalgrad(qnA, qnB, gA, gB);  // gradV(q_new); reused as next step's gradV(q)

    pA = phA - 0.5f * DT * gA; qA = qnA;
    pB = phB - 0.5f * DT * gB; qB = qnB;
  }
}

}  // namespace

extern "C" void kernel_launch(void* const* d_in, const int* in_sizes, int n_in,
                              void* d_out, int out_size, void* d_ws, size_t ws_size,
                              hipStream_t stream) {
  (void)in_sizes; (void)n_in; (void)out_size; (void)d_ws; (void)ws_size;
  const float* q0 = (const float*)d_in[0];
  const float* pd = (const float*)d_in[1];
  const float* W1 = (const float*)d_in[2];
  const float* b1 = (const float*)d_in[3];
  const float* W2 = (const float*)d_in[4];
  const float* b2 = (const float*)d_in[5];
  const float* W3 = (const float*)d_in[6];
  // d_in[7] = b3: constant offset, does not affect gradV or distances.
  float* out = (float*)d_out;

  geo_scramble_kernel<<<dim3(512), dim3(256), 0, stream>>>(q0, pd, W1, b1, W2, b2, W3, out);
}

// Round 8
// 1807.231 us; speedup vs baseline: 3.5208x; 2.2575x over previous
//
#include <hip/hip_runtime.h>
#include <math.h>

namespace {

constexpr int   STEPS = 100;
constexpr int   BATCH = 2048;
constexpr float DT    = 0.05f;
constexpr float DAMP  = 0.01f;
constexpr float EPSV  = 1e-8f;
constexpr int   NT    = 2;   // trajectories per wave (1 pair)
constexpr int   LDW   = 130; // R2-proven stride (0 conflicts measured)

__device__ __forceinline__ float wsum(float v) {
#pragma unroll
  for (int o = 32; o > 0; o >>= 1) v += __shfl_xor(v, o, 64);
  return v;
}

__global__ __launch_bounds__(256, 2)
void geo_scramble_kernel(const float* __restrict__ q0g, const float* __restrict__ pdg,
                         const float* __restrict__ W1g, const float* __restrict__ b1g,
                         const float* __restrict__ W2g, const float* __restrict__ b2g,
                         const float* __restrict__ W3g, float* __restrict__ out)
{
  // Only the transposed W2 lives in LDS (L2-fwd needs column access).
  // W1 phases (L1-fwd, BW1) and BW2 read W1g/W2g straight from global:
  // 64KB working set is L1/L2-resident, and those reads ride the vector-mem
  // pipe concurrently with the (previously saturated) DS pipe.
  __shared__ __align__(16) float W2Ts[64 * LDW];          // W2Ts[j][k] = W2[k][j]
  __shared__ __align__(16) float stg_all[4][NT][128];     // per-wave broadcast staging

  const int tid  = threadIdx.x;
  const int lane = tid & 63;
  const int wave = tid >> 6;

  for (int idx = tid; idx < 64 * 128; idx += 256) {
    int j = idx >> 7, k = idx & 127;
    W2Ts[j * LDW + k] = W2g[k * 64 + j];
  }
  __syncthreads();

  const float rb10 = b1g[2 * lane];
  const float rb11 = b1g[2 * lane + 1];
  const float rb2  = b2g[lane];
  const float rw3  = W3g[lane];

  float (*stg)[128] = stg_all[wave];
  const int pair = blockIdx.x * 4 + wave;  // one (base, perturbed) pair per wave
  const int l2 = lane << 1;

  float q[NT], p[NT], g[NT];
#pragma unroll
  for (int t = 0; t < NT; ++t) {
    float base = q0g[pair * 64 + lane];
    if (t & 1) {
      float qp = base + 1e-4f * pdg[pair * 64 + lane];
      float n  = sqrtf(wsum(qp * qp));
      float sc = (n > 0.99f) ? (0.99f / (n + EPSV)) : 1.0f;
      q[t] = qp * sc;
    } else {
      q[t] = base;
    }
    p[t] = 0.0f;
  }

  // Batched gradient of V(q) = W3 . silu(W2 . silu(W1 q + b1) + b2).
  // Lane j owns latent dim j and hidden dims {2j, 2j+1}. Broadcast staging
  // via LDS (R2-proven). FMA order per accumulator identical to R2.
  auto evalgrad = [&](const float* x, float* gr) {
#pragma unroll
    for (int t = 0; t < NT; ++t) stg[t][lane] = x[t];

    // ---- layer1 forward: z1 = W1^T q + b1 (weights from global, coalesced b64) ----
    float a0[NT], a1[NT];
#pragma unroll
    for (int t = 0; t < NT; ++t) { a0[t] = rb10; a1[t] = rb11; }
#pragma unroll 4
    for (int i = 0; i < 64; i += 4) {
      float bq[NT][4];
#pragma unroll
      for (int t = 0; t < NT; ++t) {
        float4 v = *(const float4*)&stg[t][i];
        bq[t][0] = v.x; bq[t][1] = v.y; bq[t][2] = v.z; bq[t][3] = v.w;
      }
#pragma unroll
      for (int u = 0; u < 4; ++u) {
        float2 w = *(const float2*)&W1g[(i + u) * 128 + l2];
#pragma unroll
        for (int t = 0; t < NT; ++t) {
          a0[t] = fmaf(bq[t][u], w.x, a0[t]);
          a1[t] = fmaf(bq[t][u], w.y, a1[t]);
        }
      }
    }

    // silu + derivative; stage h1
    float d10[NT], d11[NT];
#pragma unroll
    for (int t = 0; t < NT; ++t) {
      float z  = a0[t];
      float s  = 1.0f / (1.0f + expf(-z));
      float h0 = z * s;
      d10[t]   = s * (1.0f + z * (1.0f - s));
      float zb = a1[t];
      float sb = 1.0f / (1.0f + expf(-zb));
      float h1 = zb * sb;
      d11[t]   = sb * (1.0f + zb * (1.0f - sb));
      float2 hh; hh.x = h0; hh.y = h1;
      *(float2*)&stg[t][l2] = hh;
    }

    // ---- layer2 forward: z2 = W2^T h1 + b2 (W2T from LDS — transpose access) ----
    float a2[NT];
#pragma unroll
    for (int t = 0; t < NT; ++t) a2[t] = rb2;
#pragma unroll 8
    for (int k = 0; k < 128; k += 4) {
      float bh[NT][4];
#pragma unroll
      for (int t = 0; t < NT; ++t) {
        float4 v = *(const float4*)&stg[t][k];
        bh[t][0] = v.x; bh[t][1] = v.y; bh[t][2] = v.z; bh[t][3] = v.w;
      }
      float4 w = *(const float4*)&W2Ts[lane * LDW + k];
#pragma unroll
      for (int t = 0; t < NT; ++t) {
        a2[t] = fmaf(bh[t][0], w.x, a2[t]);
        a2[t] = fmaf(bh[t][1], w.y, a2[t]);
        a2[t] = fmaf(bh[t][2], w.z, a2[t]);
        a2[t] = fmaf(bh[t][3], w.w, a2[t]);
      }
    }

    // g2 = W3 * silu'(z2); stage
#pragma unroll
    for (int t = 0; t < NT; ++t) {
      float z = a2[t];
      float s = 1.0f / (1.0f + expf(-z));
      stg[t][lane] = rw3 * (s * (1.0f + z * (1.0f - s)));
    }

    // ---- backward through W2: gh1[k] = sum_j g2[j] * W2[k][j] ----
    // Lane reads W2 rows l2, l2+1 from global (16B contiguous chunks).
    // wxA[u] == old w_u.x, wxB[u] == old w_u.y: same values, same FMA order.
    float c0[NT], c1[NT];
#pragma unroll
    for (int t = 0; t < NT; ++t) { c0[t] = 0.0f; c1[t] = 0.0f; }
#pragma unroll 4
    for (int j = 0; j < 64; j += 4) {
      float bg[NT][4];
#pragma unroll
      for (int t = 0; t < NT; ++t) {
        float4 v = *(const float4*)&stg[t][j];
        bg[t][0] = v.x; bg[t][1] = v.y; bg[t][2] = v.z; bg[t][3] = v.w;
      }
      float4 wxA = *(const float4*)&W2g[l2 * 64 + j];
      float4 wxB = *(const float4*)&W2g[(l2 + 1) * 64 + j];
#pragma unroll
      for (int t = 0; t < NT; ++t) {
        c0[t] = fmaf(bg[t][0], wxA.x, c0[t]); c1[t] = fmaf(bg[t][0], wxB.x, c1[t]);
      }
#pragma unroll
      for (int t = 0; t < NT; ++t) {
        c0[t] = fmaf(bg[t][1], wxA.y, c0[t]); c1[t] = fmaf(bg[t][1], wxB.y, c1[t]);
      }
#pragma unroll
      for (int t = 0; t < NT; ++t) {
        c0[t] = fmaf(bg[t][2], wxA.z, c0[t]); c1[t] = fmaf(bg[t][2], wxB.z, c1[t]);
      }
#pragma unroll
      for (int t = 0; t < NT; ++t) {
        c0[t] = fmaf(bg[t][3], wxA.w, c0[t]); c1[t] = fmaf(bg[t][3], wxB.w, c1[t]);
      }
    }

    // g1 = gh1 * silu'(z1); stage
#pragma unroll
    for (int t = 0; t < NT; ++t) {
      float2 gg; gg.x = c0[t] * d10[t]; gg.y = c1[t] * d11[t];
      *(float2*)&stg[t][l2] = gg;
    }

    // ---- backward through W1: grad[i] = sum_k g1[k] * W1[i][k] ----
    // Lane reads its own W1 row from global (contiguous b128 chunks).
#pragma unroll
    for (int t = 0; t < NT; ++t) gr[t] = 0.0f;
#pragma unroll 8
    for (int k = 0; k < 128; k += 4) {
      float bg[NT][4];
#pragma unroll
      for (int t = 0; t < NT; ++t) {
        float4 v = *(const float4*)&stg[t][k];
        bg[t][0] = v.x; bg[t][1] = v.y; bg[t][2] = v.z; bg[t][3] = v.w;
      }
      float4 w = *(const float4*)&W1g[lane * 128 + k];
#pragma unroll
      for (int t = 0; t < NT; ++t) {
        gr[t] = fmaf(bg[t][0], w.x, gr[t]);
        gr[t] = fmaf(bg[t][1], w.y, gr[t]);
        gr[t] = fmaf(bg[t][2], w.z, gr[t]);
        gr[t] = fmaf(bg[t][3], w.w, gr[t]);
      }
    }
  };

  evalgrad(q, g);  // gradV at initial positions

  for (int s = 0; s < STEPS; ++s) {
    // wsum(q·q) computed ONCE per trajectory, shared bitwise between the
    // distance and the leapfrog (identical expression on identical bits).
    float qq0 = wsum(q[0] * q[0]);
    float qq1 = wsum(q[1] * q[1]);

    // distance BEFORE leapfrog (matches scan order)
    {
      float df = q[0] - q[1];
      float d2 = wsum(df * df);
      float x2 = fminf(qq0, 0.999f);
      float y2 = fminf(qq1, 0.999f);
      float arg = 1.0f + 2.0f * d2 / ((1.0f - x2) * (1.0f - y2) + EPSV);
      float d = acoshf(fmaxf(arg, 1.0f + EPSV));
      if (lane == 0) out[s * BATCH + pair] = d;
    }

    float qn[NT], ph[NT];
#pragma unroll
    for (int t = 0; t < NT; ++t) {
      ph[t] = (p[t] - 0.5f * DT * g[t]) * (1.0f - DAMP);
      float q2r = (t == 0) ? qq0 : qq1;
      float q2c = fminf(q2r, 0.999f);
      float lam = 2.0f / (1.0f - q2c);
      float v   = DT * ph[t] / (lam * lam);
      // exp_map(q, v)
      float vn  = sqrtf(wsum(v * v)) + EPSV;
      float mag = tanhf(fminf(lam * vn * 0.5f, 15.0f));
      float y   = mag * (v / vn);
      // mobius_add(q, y)  (x2 UNclamped here, per reference)
      float y2  = wsum(y * y);
      float xy  = wsum(q[t] * y);
      float num = (1.0f + 2.0f * xy + y2) * q[t] + (1.0f - q2r) * y;
      float den = 1.0f + 2.0f * xy + q2r * y2;
      float r   = num / (den + EPSV);
      float rn  = sqrtf(wsum(r * r));
      float sc  = (rn > 0.99f) ? (0.99f / (rn + EPSV)) : 1.0f;
      qn[t] = r * sc;
    }

    evalgrad(qn, g);  // gradV(q_new); also next step's gradV(q)
#pragma unroll
    for (int t = 0; t < NT; ++t) {
      p[t] = ph[t] - 0.5f * DT * g[t];
      q[t] = qn[t];
    }
  }
}

}  // namespace

extern "C" void kernel_launch(void* const* d_in, const int* in_sizes, int n_in,
                              void* d_out, int out_size, void* d_ws, size_t ws_size,
                              hipStream_t stream) {
  (void)in_sizes; (void)n_in; (void)out_size; (void)d_ws; (void)ws_size;
  const float* q0 = (const float*)d_in[0];
  const float* pd = (const float*)d_in[1];
  const float* W1 = (const float*)d_in[2];
  const float* b1 = (const float*)d_in[3];
  const float* W2 = (const float*)d_in[4];
  const float* b2 = (const float*)d_in[5];
  const float* W3 = (const float*)d_in[6];
  // d_in[7] = b3: constant offset, does not affect gradV or distances.
  float* out = (float*)d_out;

  geo_scramble_kernel<<<dim3(512), dim3(256), 0, stream>>>(q0, pd, W1, b1, W2, b2, W3, out);
}

// Round 10
// 934.163 us; speedup vs baseline: 6.8114x; 1.9346x over previous
//
#include <hip/hip_runtime.h>
#include <math.h>

namespace {

constexpr int   STEPS = 100;
constexpr int   BATCH = 2048;
constexpr float DT    = 0.05f;
constexpr float DAMP  = 0.01f;
constexpr float EPSV  = 1e-8f;
constexpr int   NT    = 2;   // trajectories per wave (1 pair)
constexpr int   LDW   = 130; // R2-proven stride (0 conflicts measured)

// DPP-assisted cross-lane add: src permuted by CTRL (immediate), then add.
template <int CTRL>
__device__ __forceinline__ float dpp_add(float v) {
  int t = __builtin_amdgcn_mov_dpp(__float_as_int(v), CTRL, 0xF, 0xF, true);
  return v + __int_as_float(t);
}

// Butterfly sum, bitwise-identical to the original shfl_xor(32,16,8,4,2,1)
// ladder. Stages 8/4/2/1 ride the VALU DPP path instead of the DS pipe:
//   row_ror:8  == lane^8 exactly ((l±8)%16 == l^8);
//   row_ror:4  == lane^4 or lane^(4^8) — bitwise equal after the ^8 fold
//                 (v[l]==v[l^8] bitwise, fp add commutative);
//   quad_perm[2,3,0,1] == lane^2, quad_perm[1,0,3,2] == lane^1 exactly.
__device__ __forceinline__ float wsum(float v) {
  v += __shfl_xor(v, 32, 64);   // DS (ds_permute)
  v += __shfl_xor(v, 16, 64);   // DS
  v = dpp_add<0x128>(v);        // row_ror:8  -> xor 8
  v = dpp_add<0x124>(v);        // row_ror:4  -> xor 4 (after fold)
  v = dpp_add<0x4E>(v);         // quad_perm [2,3,0,1] -> xor 2
  v = dpp_add<0xB1>(v);         // quad_perm [1,0,3,2] -> xor 1
  return v;
}

__global__ __launch_bounds__(256, 2)
void geo_scramble_kernel(const float* __restrict__ q0g, const float* __restrict__ pdg,
                         const float* __restrict__ W1g, const float* __restrict__ b1g,
                         const float* __restrict__ W2g, const float* __restrict__ b2g,
                         const float* __restrict__ W3g, float* __restrict__ out)
{
  // W1s[i][h] : [64][LDW]   W2Ts[j][k] : [64][LDW]  (W2Ts[j][k] = W2[k][j])
  // L1-fwd reads W1 straight from global (coalesced 512B/instr, L1-resident);
  // the divergent phases (L2fwd/BW2 via W2Ts, BW1 via W1s) stay in LDS.
  __shared__ __align__(16) float W1s[64 * LDW];
  __shared__ __align__(16) float W2Ts[64 * LDW];
  __shared__ __align__(16) float stg_all[4][NT][128];  // per-wave broadcast staging

  const int tid  = threadIdx.x;
  const int lane = tid & 63;
  const int wave = tid >> 6;

  for (int idx = tid; idx < 64 * 128; idx += 256) {
    int r = idx >> 7, c = idx & 127;
    W1s[r * LDW + c] = W1g[idx];
  }
  for (int idx = tid; idx < 64 * 128; idx += 256) {
    int j = idx >> 7, k = idx & 127;
    W2Ts[j * LDW + k] = W2g[k * 64 + j];
  }
  __syncthreads();

  const float rb10 = b1g[2 * lane];
  const float rb11 = b1g[2 * lane + 1];
  const float rb2  = b2g[lane];
  const float rw3  = W3g[lane];

  float (*stg)[128] = stg_all[wave];
  const int pair = blockIdx.x * 4 + wave;  // one (base, perturbed) pair per wave
  const int l2 = lane << 1;

  float q[NT], p[NT], g[NT];
#pragma unroll
  for (int t = 0; t < NT; ++t) {
    float base = q0g[pair * 64 + lane];
    if (t & 1) {
      float qp = base + 1e-4f * pdg[pair * 64 + lane];
      float n  = sqrtf(wsum(qp * qp));
      float sc = (n > 0.99f) ? (0.99f / (n + EPSV)) : 1.0f;
      q[t] = qp * sc;
    } else {
      q[t] = base;
    }
    p[t] = 0.0f;
  }

  // Batched gradient of V(q) = W3 . silu(W2 . silu(W1 q + b1) + b2).
  // Lane j owns latent dim j and hidden dims {2j, 2j+1}. Broadcast staging
  // via LDS (R2-proven). FMA order per accumulator identical to R2.
  auto evalgrad = [&](const float* x, float* gr) {
#pragma unroll
    for (int t = 0; t < NT; ++t) stg[t][lane] = x[t];

    // ---- layer1 forward: z1 = W1^T q + b1 (weights from GLOBAL, coalesced) ----
    float a0[NT], a1[NT];
#pragma unroll
    for (int t = 0; t < NT; ++t) { a0[t] = rb10; a1[t] = rb11; }
#pragma unroll 4
    for (int i = 0; i < 64; i += 4) {
      float bq[NT][4];
#pragma unroll
      for (int t = 0; t < NT; ++t) {
        float4 v = *(const float4*)&stg[t][i];
        bq[t][0] = v.x; bq[t][1] = v.y; bq[t][2] = v.z; bq[t][3] = v.w;
      }
#pragma unroll
      for (int u = 0; u < 4; ++u) {
        float2 w = *(const float2*)&W1g[(i + u) * 128 + l2];
#pragma unroll
        for (int t = 0; t < NT; ++t) {
          a0[t] = fmaf(bq[t][u], w.x, a0[t]);
          a1[t] = fmaf(bq[t][u], w.y, a1[t]);
        }
      }
    }

    // silu + derivative; stage h1
    float d10[NT], d11[NT];
#pragma unroll
    for (int t = 0; t < NT; ++t) {
      float z  = a0[t];
      float s  = 1.0f / (1.0f + expf(-z));
      float h0 = z * s;
      d10[t]   = s * (1.0f + z * (1.0f - s));
      float zb = a1[t];
      float sb = 1.0f / (1.0f + expf(-zb));
      float h1 = zb * sb;
      d11[t]   = sb * (1.0f + zb * (1.0f - sb));
      float2 hh; hh.x = h0; hh.y = h1;
      *(float2*)&stg[t][l2] = hh;
    }

    // ---- layer2 forward: z2 = W2^T h1 + b2 (W2T rows from LDS) ----
    float a2[NT];
#pragma unroll
    for (int t = 0; t < NT; ++t) a2[t] = rb2;
#pragma unroll 8
    for (int k = 0; k < 128; k += 4) {
      float bh[NT][4];
#pragma unroll
      for (int t = 0; t < NT; ++t) {
        float4 v = *(const float4*)&stg[t][k];
        bh[t][0] = v.x; bh[t][1] = v.y; bh[t][2] = v.z; bh[t][3] = v.w;
      }
      float4 w = *(const float4*)&W2Ts[lane * LDW + k];
#pragma unroll
      for (int t = 0; t < NT; ++t) {
        a2[t] = fmaf(bh[t][0], w.x, a2[t]);
        a2[t] = fmaf(bh[t][1], w.y, a2[t]);
        a2[t] = fmaf(bh[t][2], w.z, a2[t]);
        a2[t] = fmaf(bh[t][3], w.w, a2[t]);
      }
    }

    // g2 = W3 * silu'(z2); stage
#pragma unroll
    for (int t = 0; t < NT; ++t) {
      float z = a2[t];
      float s = 1.0f / (1.0f + expf(-z));
      stg[t][lane] = rw3 * (s * (1.0f + z * (1.0f - s)));
    }

    // ---- backward through W2: gh1[k] = sum_j g2[j] * W2[k][j] (LDS columns) ----
    float c0[NT], c1[NT];
#pragma unroll
    for (int t = 0; t < NT; ++t) { c0[t] = 0.0f; c1[t] = 0.0f; }
#pragma unroll 4
    for (int j = 0; j < 64; j += 4) {
      float bg[NT][4];
#pragma unroll
      for (int t = 0; t < NT; ++t) {
        float4 v = *(const float4*)&stg[t][j];
        bg[t][0] = v.x; bg[t][1] = v.y; bg[t][2] = v.z; bg[t][3] = v.w;
      }
#pragma unroll
      for (int u = 0; u < 4; ++u) {
        float2 w = *(const float2*)&W2Ts[(j + u) * LDW + l2];
#pragma unroll
        for (int t = 0; t < NT; ++t) {
          float s = bg[t][u];
          c0[t] = fmaf(s, w.x, c0[t]);
          c1[t] = fmaf(s, w.y, c1[t]);
        }
      }
    }

    // g1 = gh1 * silu'(z1); stage
#pragma unroll
    for (int t = 0; t < NT; ++t) {
      float2 gg; gg.x = c0[t] * d10[t]; gg.y = c1[t] * d11[t];
      *(float2*)&stg[t][l2] = gg;
    }

    // ---- backward through W1: grad[i] = sum_k g1[k] * W1[i][k] (LDS rows) ----
#pragma unroll
    for (int t = 0; t < NT; ++t) gr[t] = 0.0f;
#pragma unroll 8
    for (int k = 0; k < 128; k += 4) {
      float bg[NT][4];
#pragma unroll
      for (int t = 0; t < NT; ++t) {
        float4 v = *(const float4*)&stg[t][k];
        bg[t][0] = v.x; bg[t][1] = v.y; bg[t][2] = v.z; bg[t][3] = v.w;
      }
      float4 w = *(const float4*)&W1s[lane * LDW + k];
#pragma unroll
      for (int t = 0; t < NT; ++t) {
        gr[t] = fmaf(bg[t][0], w.x, gr[t]);
        gr[t] = fmaf(bg[t][1], w.y, gr[t]);
        gr[t] = fmaf(bg[t][2], w.z, gr[t]);
        gr[t] = fmaf(bg[t][3], w.w, gr[t]);
      }
    }
  };

  evalgrad(q, g);  // gradV at initial positions

  for (int s = 0; s < STEPS; ++s) {
    // wsum(q·q) computed once per trajectory, shared bitwise between the
    // distance and the leapfrog (identical expression on identical bits).
    float qq0 = wsum(q[0] * q[0]);
    float qq1 = wsum(q[1] * q[1]);

    // distance BEFORE leapfrog (matches scan order)
    {
      float df = q[0] - q[1];
      float d2 = wsum(df * df);
      float x2 = fminf(qq0, 0.999f);
      float y2 = fminf(qq1, 0.999f);
      float arg = 1.0f + 2.0f * d2 / ((1.0f - x2) * (1.0f - y2) + EPSV);
      float d = acoshf(fmaxf(arg, 1.0f + EPSV));
      if (lane == 0) out[s * BATCH + pair] = d;
    }

    float qn[NT], ph[NT];
#pragma unroll
    for (int t = 0; t < NT; ++t) {
      ph[t] = (p[t] - 0.5f * DT * g[t]) * (1.0f - DAMP);
      float q2r = (t == 0) ? qq0 : qq1;
      float q2c = fminf(q2r, 0.999f);
      float lam = 2.0f / (1.0f - q2c);
      float v   = DT * ph[t] / (lam * lam);
      // exp_map(q, v)
      float vn  = sqrtf(wsum(v * v)) + EPSV;
      float mag = tanhf(fminf(lam * vn * 0.5f, 15.0f));
      float y   = mag * (v / vn);
      // mobius_add(q, y)  (x2 UNclamped here, per reference)
      float y2  = wsum(y * y);
      float xy  = wsum(q[t] * y);
      float num = (1.0f + 2.0f * xy + y2) * q[t] + (1.0f - q2r) * y;
      float den = 1.0f + 2.0f * xy + q2r * y2;
      float r   = num / (den + EPSV);
      float rn  = sqrtf(wsum(r * r));
      float sc  = (rn > 0.99f) ? (0.99f / (rn + EPSV)) : 1.0f;
      qn[t] = r * sc;
    }

    evalgrad(qn, g);  // gradV(q_new); also next step's gradV(q)
#pragma unroll
    for (int t = 0; t < NT; ++t) {
      p[t] = ph[t] - 0.5f * DT * g[t];
      q[t] = qn[t];
    }
  }
}

}  // namespace

extern "C" void kernel_launch(void* const* d_in, const int* in_sizes, int n_in,
                              void* d_out, int out_size, void* d_ws, size_t ws_size,
                              hipStream_t stream) {
  (void)in_sizes; (void)n_in; (void)out_size; (void)d_ws; (void)ws_size;
  const float* q0 = (const float*)d_in[0];
  const float* pd = (const float*)d_in[1];
  const float* W1 = (const float*)d_in[2];
  const float* b1 = (const float*)d_in[3];
  const float* W2 = (const float*)d_in[4];
  const float* b2 = (const float*)d_in[5];
  const float* W3 = (const float*)d_in[6];
  // d_in[7] = b3: constant offset, does not affect gradV or distances.
  float* out = (float*)d_out;

  geo_scramble_kernel<<<dim3(512), dim3(256), 0, stream>>>(q0, pd, W1, b1, W2, b2, W3, out);
}

// Round 11
// 873.660 us; speedup vs baseline: 7.2831x; 1.0693x over previous
//
#include <hip/hip_runtime.h>
#include <math.h>

namespace {

constexpr int   STEPS = 100;
constexpr int   BATCH = 2048;
constexpr float DT    = 0.05f;
constexpr float DAMP  = 0.01f;
constexpr float EPSV  = 1e-8f;
constexpr int   LDW   = 130; // R2-proven stride (0 conflicts measured)

typedef float f32x2 __attribute__((ext_vector_type(2)));

// Dual FP32 FMA (one VOP3P issue). acc.lo += s.lo*w.SEL; acc.hi += s.hi*w.SEL.
// Weight-half replication via op_sel (no splat movs). Each half is an exact
// IEEE FMA -> bitwise-identical to the scalar fmaf pair it replaces.
__device__ __forceinline__ void pk_wlo(f32x2& acc, f32x2 s, f32x2 w) {
  asm("v_pk_fma_f32 %0, %1, %2, %0 op_sel:[0,0,0] op_sel_hi:[1,0,1]"
      : "+v"(acc) : "v"(s), "v"(w));
}
__device__ __forceinline__ void pk_whi(f32x2& acc, f32x2 s, f32x2 w) {
  asm("v_pk_fma_f32 %0, %1, %2, %0 op_sel:[0,1,0] op_sel_hi:[1,1,1]"
      : "+v"(acc) : "v"(s), "v"(w));
}

// DPP-assisted cross-lane add: src permuted by CTRL (immediate), then add.
template <int CTRL>
__device__ __forceinline__ float dpp_add(float v) {
  int t = __builtin_amdgcn_mov_dpp(__float_as_int(v), CTRL, 0xF, 0xF, true);
  return v + __int_as_float(t);
}

// Butterfly sum, bitwise-identical to shfl_xor(32,16,8,4,2,1) ladder;
// stages 8/4/2/1 on the VALU DPP path (see R10 notes).
__device__ __forceinline__ float wsum(float v) {
  v += __shfl_xor(v, 32, 64);   // DS (ds_permute)
  v += __shfl_xor(v, 16, 64);   // DS
  v = dpp_add<0x128>(v);        // row_ror:8  -> xor 8
  v = dpp_add<0x124>(v);        // row_ror:4  -> xor 4 (after fold)
  v = dpp_add<0x4E>(v);         // quad_perm [2,3,0,1] -> xor 2
  v = dpp_add<0xB1>(v);         // quad_perm [1,0,3,2] -> xor 1
  return v;
}

__global__ __launch_bounds__(256, 2)
void geo_scramble_kernel(const float* __restrict__ q0g, const float* __restrict__ pdg,
                         const float* __restrict__ W1g, const float* __restrict__ b1g,
                         const float* __restrict__ W2g, const float* __restrict__ b2g,
                         const float* __restrict__ W3g, float* __restrict__ out)
{
  // W1s[i][h] : [64][LDW]   W2Ts[j][k] : [64][LDW]  (W2Ts[j][k] = W2[k][j])
  // L1-fwd weights come straight from global (coalesced, L1-resident).
  // Staging is INTERLEAVED: stg[2*elem + traj] so every b128 staging read
  // returns (A,B) pairs ready for v_pk_fma_f32.
  __shared__ __align__(16) float W1s[64 * LDW];
  __shared__ __align__(16) float W2Ts[64 * LDW];
  __shared__ __align__(16) float stg_all[4][256];

  const int tid  = threadIdx.x;
  const int lane = tid & 63;
  const int wave = tid >> 6;

  for (int idx = tid; idx < 64 * 128; idx += 256) {
    int r = idx >> 7, c = idx & 127;
    W1s[r * LDW + c] = W1g[idx];
  }
  for (int idx = tid; idx < 64 * 128; idx += 256) {
    int j = idx >> 7, k = idx & 127;
    W2Ts[j * LDW + k] = W2g[k * 64 + j];
  }
  __syncthreads();

  const float rb10 = b1g[2 * lane];
  const float rb11 = b1g[2 * lane + 1];
  const float rb2  = b2g[lane];
  const float rw3  = W3g[lane];

  float* stgI = stg_all[wave];
  const int pair = blockIdx.x * 4 + wave;  // one (base, perturbed) pair per wave
  const int l2 = lane << 1;

  float qA = q0g[pair * 64 + lane];
  float qB;
  {
    float qp = qA + 1e-4f * pdg[pair * 64 + lane];
    float n  = sqrtf(wsum(qp * qp));
    float sc = (n > 0.99f) ? (0.99f / (n + EPSV)) : 1.0f;
    qB = qp * sc;
  }
  float pA = 0.0f, pB = 0.0f, gA, gB;

  // Batched gradient of V(q) = W3 . silu(W2 . silu(W1 q + b1) + b2) for the
  // (base, perturbed) pair. Lane j owns latent dim j and hidden dims
  // {2j, 2j+1}. Both trajectories ride each v_pk_fma_f32; per-accumulator
  // FMA order is element-ascending, identical to R10 (bitwise-stable).
  auto evalgrad = [&](float xA, float xB, float& grA, float& grB) {
    {
      f32x2 xx; xx.x = xA; xx.y = xB;
      *(f32x2*)&stgI[l2] = xx;                 // elem=lane pair
    }

    // ---- layer1 forward: z1 = W1^T q + b1 (weights from GLOBAL, coalesced) ----
    f32x2 acc0; acc0.x = rb10; acc0.y = rb10;  // (a0A, a0B)
    f32x2 acc1; acc1.x = rb11; acc1.y = rb11;  // (a1A, a1B)
#pragma unroll 4
    for (int i = 0; i < 64; i += 4) {
      float4 v0 = *(const float4*)&stgI[2 * i];       // elems i, i+1 (A,B pairs)
      float4 v1 = *(const float4*)&stgI[2 * i + 4];   // elems i+2, i+3
      f32x2 p0; p0.x = v0.x; p0.y = v0.y;
      f32x2 p1; p1.x = v0.z; p1.y = v0.w;
      f32x2 p2; p2.x = v1.x; p2.y = v1.y;
      f32x2 p3; p3.x = v1.z; p3.y = v1.w;
      f32x2 w0 = *(const f32x2*)&W1g[(i + 0) * 128 + l2];
      f32x2 w1 = *(const f32x2*)&W1g[(i + 1) * 128 + l2];
      f32x2 w2 = *(const f32x2*)&W1g[(i + 2) * 128 + l2];
      f32x2 w3 = *(const f32x2*)&W1g[(i + 3) * 128 + l2];
      pk_wlo(acc0, p0, w0); pk_whi(acc1, p0, w0);
      pk_wlo(acc0, p1, w1); pk_whi(acc1, p1, w1);
      pk_wlo(acc0, p2, w2); pk_whi(acc1, p2, w2);
      pk_wlo(acc0, p3, w3); pk_whi(acc1, p3, w3);
    }

    // silu + derivative (scalar, identical op sequence); stage h interleaved
    float a0A = acc0.x, a0B = acc0.y, a1A = acc1.x, a1B = acc1.y;
    float sA0 = 1.0f / (1.0f + expf(-a0A));
    float h0A = a0A * sA0;
    float d10A = sA0 * (1.0f + a0A * (1.0f - sA0));
    float sA1 = 1.0f / (1.0f + expf(-a1A));
    float h1A = a1A * sA1;
    float d11A = sA1 * (1.0f + a1A * (1.0f - sA1));
    float sB0 = 1.0f / (1.0f + expf(-a0B));
    float h0B = a0B * sB0;
    float d10B = sB0 * (1.0f + a0B * (1.0f - sB0));
    float sB1 = 1.0f / (1.0f + expf(-a1B));
    float h1B = a1B * sB1;
    float d11B = sB1 * (1.0f + a1B * (1.0f - sB1));
    {
      float4 hh; hh.x = h0A; hh.y = h0B; hh.z = h1A; hh.w = h1B;
      *(float4*)&stgI[4 * lane] = hh;          // elems 2l, 2l+1 pairs
    }

    // ---- layer2 forward: z2 = W2^T h1 + b2 (W2T rows from LDS) ----
    f32x2 acc2; acc2.x = rb2; acc2.y = rb2;    // (a2A, a2B)
#pragma unroll 8
    for (int k = 0; k < 128; k += 4) {
      float4 v0 = *(const float4*)&stgI[2 * k];
      float4 v1 = *(const float4*)&stgI[2 * k + 4];
      f32x2 p0; p0.x = v0.x; p0.y = v0.y;
      f32x2 p1; p1.x = v0.z; p1.y = v0.w;
      f32x2 p2; p2.x = v1.x; p2.y = v1.y;
      f32x2 p3; p3.x = v1.z; p3.y = v1.w;
      float4 w4 = *(const float4*)&W2Ts[lane * LDW + k];
      f32x2 w01; w01.x = w4.x; w01.y = w4.y;
      f32x2 w23; w23.x = w4.z; w23.y = w4.w;
      pk_wlo(acc2, p0, w01);   // += h[k]   * w4.x
      pk_whi(acc2, p1, w01);   // += h[k+1] * w4.y
      pk_wlo(acc2, p2, w23);   // += h[k+2] * w4.z
      pk_whi(acc2, p3, w23);   // += h[k+3] * w4.w
    }

    // g2 = W3 * silu'(z2); stage interleaved
    {
      float a2A = acc2.x, a2B = acc2.y;
      float t2A = 1.0f / (1.0f + expf(-a2A));
      float g2A = rw3 * (t2A * (1.0f + a2A * (1.0f - t2A)));
      float t2B = 1.0f / (1.0f + expf(-a2B));
      float g2B = rw3 * (t2B * (1.0f + a2B * (1.0f - t2B)));
      f32x2 gg; gg.x = g2A; gg.y = g2B;
      *(f32x2*)&stgI[l2] = gg;
    }

    // ---- backward through W2: gh1[k] = sum_j g2[j] * W2[k][j] (LDS columns) ----
    f32x2 c0; c0.x = 0.0f; c0.y = 0.0f;        // (c0A, c0B)
    f32x2 c1; c1.x = 0.0f; c1.y = 0.0f;        // (c1A, c1B)
#pragma unroll 4
    for (int j = 0; j < 64; j += 4) {
      float4 v0 = *(const float4*)&stgI[2 * j];
      float4 v1 = *(const float4*)&stgI[2 * j + 4];
      f32x2 p0; p0.x = v0.x; p0.y = v0.y;
      f32x2 p1; p1.x = v0.z; p1.y = v0.w;
      f32x2 p2; p2.x = v1.x; p2.y = v1.y;
      f32x2 p3; p3.x = v1.z; p3.y = v1.w;
      f32x2 w0 = *(const f32x2*)&W2Ts[(j + 0) * LDW + l2];
      f32x2 w1 = *(const f32x2*)&W2Ts[(j + 1) * LDW + l2];
      f32x2 w2 = *(const f32x2*)&W2Ts[(j + 2) * LDW + l2];
      f32x2 w3 = *(const f32x2*)&W2Ts[(j + 3) * LDW + l2];
      pk_wlo(c0, p0, w0); pk_whi(c1, p0, w0);
      pk_wlo(c0, p1, w1); pk_whi(c1, p1, w1);
      pk_wlo(c0, p2, w2); pk_whi(c1, p2, w2);
      pk_wlo(c0, p3, w3); pk_whi(c1, p3, w3);
    }

    // g1 = gh1 * silu'(z1); stage interleaved
    {
      float4 gg;
      gg.x = c0.x * d10A; gg.y = c0.y * d10B;
      gg.z = c1.x * d11A; gg.w = c1.y * d11B;
      *(float4*)&stgI[4 * lane] = gg;
    }

    // ---- backward through W1: grad[i] = sum_k g1[k] * W1[i][k] (LDS rows) ----
    f32x2 gr; gr.x = 0.0f; gr.y = 0.0f;        // (grA, grB)
#pragma unroll 8
    for (int k = 0; k < 128; k += 4) {
      float4 v0 = *(const float4*)&stgI[2 * k];
      float4 v1 = *(const float4*)&stgI[2 * k + 4];
      f32x2 p0; p0.x = v0.x; p0.y = v0.y;
      f32x2 p1; p1.x = v0.z; p1.y = v0.w;
      f32x2 p2; p2.x = v1.x; p2.y = v1.y;
      f32x2 p3; p3.x = v1.z; p3.y = v1.w;
      float4 w4 = *(const float4*)&W1s[lane * LDW + k];
      f32x2 w01; w01.x = w4.x; w01.y = w4.y;
      f32x2 w23; w23.x = w4.z; w23.y = w4.w;
      pk_wlo(gr, p0, w01);
      pk_whi(gr, p1, w01);
      pk_wlo(gr, p2, w23);
      pk_whi(gr, p3, w23);
    }
    grA = gr.x; grB = gr.y;
  };

  evalgrad(qA, qB, gA, gB);  // gradV at initial positions

  for (int s = 0; s < STEPS; ++s) {
    // wsum(q·q) computed once per trajectory, shared bitwise between the
    // distance and the leapfrog (identical expression on identical bits).
    float qq0 = wsum(qA * qA);
    float qq1 = wsum(qB * qB);

    // distance BEFORE leapfrog (matches scan order)
    {
      float df = qA - qB;
      float d2 = wsum(df * df);
      float x2 = fminf(qq0, 0.999f);
      float y2 = fminf(qq1, 0.999f);
      float arg = 1.0f + 2.0f * d2 / ((1.0f - x2) * (1.0f - y2) + EPSV);
      float d = acoshf(fmaxf(arg, 1.0f + EPSV));
      if (lane == 0) out[s * BATCH + pair] = d;
    }

    // leapfrog first half, trajectory A (R10 op sequence, unchanged)
    float qnA, phA;
    {
      float ph  = (pA - 0.5f * DT * gA) * (1.0f - DAMP);
      float q2r = qq0;
      float q2c = fminf(q2r, 0.999f);
      float lam = 2.0f / (1.0f - q2c);
      float v   = DT * ph / (lam * lam);
      float vn  = sqrtf(wsum(v * v)) + EPSV;
      float mag = tanhf(fminf(lam * vn * 0.5f, 15.0f));
      float y   = mag * (v / vn);
      float y2  = wsum(y * y);
      float xy  = wsum(qA * y);
      float num = (1.0f + 2.0f * xy + y2) * qA + (1.0f - q2r) * y;
      float den = 1.0f + 2.0f * xy + q2r * y2;
      float r   = num / (den + EPSV);
      float rn  = sqrtf(wsum(r * r));
      float sc  = (rn > 0.99f) ? (0.99f / (rn + EPSV)) : 1.0f;
      qnA = r * sc;
      phA = ph;
    }
    // leapfrog first half, trajectory B
    float qnB, phB;
    {
      float ph  = (pB - 0.5f * DT * gB) * (1.0f - DAMP);
      float q2r = qq1;
      float q2c = fminf(q2r, 0.999f);
      float lam = 2.0f / (1.0f - q2c);
      float v   = DT * ph / (lam * lam);
      float vn  = sqrtf(wsum(v * v)) + EPSV;
      float mag = tanhf(fminf(lam * vn * 0.5f, 15.0f));
      float y   = mag * (v / vn);
      float y2  = wsum(y * y);
      float xy  = wsum(qB * y);
      float num = (1.0f + 2.0f * xy + y2) * qB + (1.0f - q2r) * y;
      float den = 1.0f + 2.0f * xy + q2r * y2;
      float r   = num / (den + EPSV);
      float rn  = sqrtf(wsum(r * r));
      float sc  = (rn > 0.99f) ? (0.99f / (rn + EPSV)) : 1.0f;
      qnB = r * sc;
      phB = ph;
    }

    evalgrad(qnA, qnB, gA, gB);  // gradV(q_new); reused as next step's gradV(q)

    pA = phA - 0.5f * DT * gA; qA = qnA;
    pB = phB - 0.5f * DT * gB; qB = qnB;
  }
}

}  // namespace

extern "C" void kernel_launch(void* const* d_in, const int* in_sizes, int n_in,
                              void* d_out, int out_size, void* d_ws, size_t ws_size,
                              hipStream_t stream) {
  (void)in_sizes; (void)n_in; (void)out_size; (void)d_ws; (void)ws_size;
  const float* q0 = (const float*)d_in[0];
  const float* pd = (const float*)d_in[1];
  const float* W1 = (const float*)d_in[2];
  const float* b1 = (const float*)d_in[3];
  const float* W2 = (const float*)d_in[4];
  const float* b2 = (const float*)d_in[5];
  const float* W3 = (const float*)d_in[6];
  // d_in[7] = b3: constant offset, does not affect gradV or distances.
  float* out = (float*)d_out;

  geo_scramble_kernel<<<dim3(512), dim3(256), 0, stream>>>(q0, pd, W1, b1, W2, b2, W3, out);
}